// Round 14
// baseline (113.447 us; speedup 1.0000x reference)
//
#include <hip/hip_runtime.h>
#include <math.h>

#define HH 1080
#define WW 1920
#define RAD 5
#define TX 32
#define TY 16            // LDS 7 planes x 26 x 42 x 4B = 30576 -> 5 blocks/CU
#define RPT 2
#define BDY 8            // 256 threads = 4 waves (R12 lesson: 4-wave blocks only)
#define LR (TY + 2*RAD)  // 26
#define LC (TX + 2*RAD)  // 42

typedef float f32x2 __attribute__((ext_vector_type(2)));

__device__ __forceinline__ float fast_rcp(float x) {
#if __has_builtin(__builtin_amdgcn_rcpf)
    return __builtin_amdgcn_rcpf(x);
#else
    return 1.0f / x;
#endif
}
__device__ __forceinline__ float fast_rsq(float x) {
#if __has_builtin(__builtin_amdgcn_rsqf)
    return __builtin_amdgcn_rsqf(x);
#else
    return rsqrtf(x);
#endif
}
__device__ __forceinline__ float fast_exp2(float x) {
#if __has_builtin(__builtin_amdgcn_exp2f)
    return __builtin_amdgcn_exp2f(x);
#else
    return exp2f(x);
#endif
}
__device__ __forceinline__ f32x2 splat(float v) { f32x2 r; r.x = v; r.y = v; return r; }

// Weight: w = exp(-d2/8) * clip(dot,0,1)^128 * exp(-|tz-z| / max(dz*sqrt(d2), 1e-4))
// One exp2; quadratic ln(1+t) ~= t - t^2/2 with t = dot-1 folded out:
//   e2 = fma(dot, fma(dot, -C/2, 2C), fma(-|zd|, tm[d2], cx[d2])),  C = 128*log2e
//   cx[d2] = -d2*log2e/8 - 1.5C;  tm[d2] = min(rdz*rsqrt(d2), 1e4*log2e);
//   rdz = min(log2e*rcp(dz), 1e10);  1/max(a,eps) == min(1/a,1/eps).
// R14: PACKED FP32 (v_pk_fma_f32, CDNA 2x f32 rate) across adjacent dx pairs.
//   LDS is SoA (7 scalar planes) so tap pairs are adjacent dwords (ds_read2_b32);
//   center-side operands splat ONCE (loop-invariant). 5 pairs + 1 scalar column.
//   VOP3P has no abs modifier -> |zd| = 2 scalar ops; neg folds as modifier.
// tm RATIO-CHAIN across rows (tm[o=1]@r == tm[o=0]@(r-1) * rr1, exact), 6 rsq/row.
// Center tap: rsqrt(0)=inf -> tm=BIG; zd=0 -> fma(-0,BIG,cx)=cx; dot=1 -> w=1. Exact.
// dot=0 (clip / zero halo mask) -> e2 <= -277 -> w=0 == reference t_m mask.
// Validated numerics R2-R13: absmax 3.9e-3 vs threshold 2e-2 (math here bit-identical).
// Lessons: R2 no full row unroll; R4 registers not LDS; R9/R10 minimal chain state;
// R11 no launch_bounds wave demands beyond VGPR fit; R12 4-wave blocks only;
// R13 occupancy realization saturates ~0.6 -> attack VALU op count (this round).

#define NCf   (-0.18033688011112042f)    // -log2e/8
#define CBf   (-276.997447850681f)       // -1.5*C bias
#define PAf   (-92.332482616893665f)     // -C/2
#define PBf   (369.32993046757466f)      // 2*C
#define BIGT  (14426.950408889634f)      // 1e4*log2e
#define K25NC (25.0f * NCf)

__global__ __launch_bounds__(TX*BDY, 4)
void denoise_kernel(const float* __restrict__ in, float* __restrict__ out) {
    __shared__ float sC0[LR][LC], sC1[LR][LC], sC2[LR][LC];   // color planes
    __shared__ float sN0[LR][LC], sN1[LR][LC], sN2[LR][LC];   // unit-normal planes
    __shared__ float sZv[LR][LC];                             // depth plane  (30576 B)

    const int tx = threadIdx.x;
    const int ty = threadIdx.y;
    const int tid = ty * TX + tx;
    const int x0 = blockIdx.x * TX;
    const int y0 = blockIdx.y * TY;

    // ---- stage tile + halo into SoA planes, normalizing normals on the fly ----
    #pragma unroll
    for (int i = 0; i < (LR * LC + TX * BDY - 1) / (TX * BDY); ++i) {
        int idx = tid + i * (TX * BDY);
        if (idx < LR * LC) {
            int r = idx / LC, c = idx % LC;
            int gx = x0 + c - RAD;
            int gy = y0 + r - RAD;
            float4 a = make_float4(0.f, 0.f, 0.f, 0.f);
            float4 b = make_float4(0.f, 0.f, 0.f, 0.f);
            if ((unsigned)gx < (unsigned)WW && (unsigned)gy < (unsigned)HH) {
                const float4* p = reinterpret_cast<const float4*>(in + ((size_t)gy * WW + gx) * 8);
                a = p[0];
                b = p[1];
            }
            float nn = a.w * a.w + b.x * b.x + b.y * b.y;
            float s = fast_rsq(fmaxf(nn, 1e-20f));
            sC0[r][c] = a.x; sC1[r][c] = a.y; sC2[r][c] = a.z;
            sN0[r][c] = a.w * s; sN1[r][c] = b.x * s; sN2[r][c] = b.y * s;
            sZv[r][c] = b.z;
        }
    }
    __syncthreads();

    // ---- per-thread centers (splat to pairs once; loop-invariant) ----
    f32x2 cn0p[RPT], cn1p[RPT], cn2p[RPT], czp[RPT];
    float rdz[RPT];
    #pragma unroll
    for (int o = 0; o < RPT; ++o) {
        int rr = ty * RPT + RAD + o, cc = tx + RAD;
        cn0p[o] = splat(sN0[rr][cc]);
        cn1p[o] = splat(sN1[rr][cc]);
        cn2p[o] = splat(sN2[rr][cc]);
        czp[o]  = splat(sZv[rr][cc]);
        int gy = y0 + ty * RPT + o;
        float dzv = 1.0f;
        if (gy < HH) dzv = in[(((size_t)gy * WW) + (x0 + tx)) * 8 + 7];
        rdz[o] = fminf(1.4426950408889634f * fast_rcp(dzv), 1e10f);
    }
    const float rr1 = rdz[1] * fast_rcp(rdz[0]);   // chain ratio, finite positive
    const f32x2 PAp = splat(PAf), PBp = splat(PBf);
    // k-pairs per j (dx pair {2j,2j+1} -> k = |dx-5|): and the packed -k^2*log2e/8 terms
    const f32x2 K2C[5] = { {25.f*NCf, 16.f*NCf}, {9.f*NCf, 4.f*NCf}, {NCf, 0.0f},
                           {NCf, 4.f*NCf},       {9.f*NCf, 16.f*NCf} };

    f32x2 ax2[RPT], ay2[RPT], az2[RPT], aw2[RPT];
    float sxl[RPT], syl[RPT], szl[RPT], swl[RPT];
    #pragma unroll
    for (int o = 0; o < RPT; ++o) {
        ax2[o] = splat(0.f); ay2[o] = splat(0.f); az2[o] = splat(0.f); aw2[o] = splat(0.f);
        sxl[o] = syl[o] = szl[o] = swl[o] = 0.f;
    }

    // unclamped tm chain state
    float tmu0[RAD + 1] = {}, tmu1[RAD + 1] = {};

    #define ROW_BODY(CHECK)                                                          \
    {                                                                                \
        _Pragma("unroll")                                                            \
        for (int k = 0; k <= RAD; ++k) tmu1[k] = tmu0[k] * rr1;                      \
        if (!CHECK || r <= 2 * RAD) {                                                \
            int dy0 = r - RAD;                                                       \
            float dy0sq = (float)(dy0 * dy0);                                        \
            _Pragma("unroll")                                                        \
            for (int k = 0; k <= RAD; ++k)                                           \
                tmu0[k] = rdz[0] * fast_rsq(dy0sq + (float)(k * k));                 \
        }                                                                            \
        constexpr int JK0[5] = {5, 3, 1, 1, 3};                                      \
        constexpr int JK1[5] = {4, 2, 0, 2, 4};                                      \
        bool  val[RPT];                                                              \
        f32x2 tm2v[RPT][5], bneg2[RPT];                                              \
        float tm5[RPT];                                                              \
        _Pragma("unroll")                                                            \
        for (int o = 0; o < RPT; ++o) {                                              \
            int dy = r - RAD - o;                                                    \
            val[o] = (dy >= -RAD) && (dy <= RAD);                                    \
            if (!CHECK || val[o]) {                                                  \
                float dy2f = (float)(dy * dy);                                       \
                bneg2[o] = splat(fmaf(dy2f, NCf, CBf));                              \
                _Pragma("unroll")                                                    \
                for (int j = 0; j < 5; ++j) {                                        \
                    float ta = (o == 0) ? tmu0[JK0[j]] : tmu1[JK0[j]];               \
                    float tb = (o == 0) ? tmu0[JK1[j]] : tmu1[JK1[j]];               \
                    tm2v[o][j].x = fminf(ta, BIGT);                                  \
                    tm2v[o][j].y = fminf(tb, BIGT);                                  \
                }                                                                    \
                tm5[o] = fminf((o == 0) ? tmu0[5] : tmu1[5], BIGT);                  \
            }                                                                        \
        }                                                                            \
        const int rr_ = ty * RPT + r;                                                \
        _Pragma("unroll")                                                            \
        for (int j = 0; j < 5; ++j) {                                                \
            const int cA = tx + 2 * j, cB = cA + 1;                                  \
            f32x2 pC0 = {sC0[rr_][cA], sC0[rr_][cB]};                                \
            f32x2 pC1 = {sC1[rr_][cA], sC1[rr_][cB]};                                \
            f32x2 pC2 = {sC2[rr_][cA], sC2[rr_][cB]};                                \
            f32x2 pN0 = {sN0[rr_][cA], sN0[rr_][cB]};                                \
            f32x2 pN1 = {sN1[rr_][cA], sN1[rr_][cB]};                                \
            f32x2 pN2 = {sN2[rr_][cA], sN2[rr_][cB]};                                \
            f32x2 pZ  = {sZv[rr_][cA], sZv[rr_][cB]};                                \
            _Pragma("unroll")                                                        \
            for (int o = 0; o < RPT; ++o) {                                          \
                if (!CHECK || val[o]) {                                              \
                    f32x2 dd = __builtin_elementwise_fma(pN0, cn0p[o],               \
                                __builtin_elementwise_fma(pN1, cn1p[o],              \
                                                          pN2 * cn2p[o]));           \
                    f32x2 vv = __builtin_elementwise_fma(dd, PAp, PBp);              \
                    f32x2 zd = pZ - czp[o];                                          \
                    f32x2 zb; zb.x = fabsf(zd.x); zb.y = fabsf(zd.y);                \
                    f32x2 cx2 = K2C[j] + bneg2[o];                                   \
                    f32x2 ea = __builtin_elementwise_fma(-zb, tm2v[o][j], cx2);      \
                    f32x2 e2 = __builtin_elementwise_fma(dd, vv, ea);                \
                    f32x2 w2; w2.x = fast_exp2(e2.x); w2.y = fast_exp2(e2.y);        \
                    ax2[o] = __builtin_elementwise_fma(pC0, w2, ax2[o]);             \
                    ay2[o] = __builtin_elementwise_fma(pC1, w2, ay2[o]);             \
                    az2[o] = __builtin_elementwise_fma(pC2, w2, az2[o]);             \
                    aw2[o] = aw2[o] + w2;                                            \
                }                                                                    \
            }                                                                        \
        }                                                                            \
        {   /* leftover column dx = 10 (k = 5), scalar path (free abs via modifier) */ \
            const int cL = tx + 10;                                                  \
            float C0s = sC0[rr_][cL], C1s = sC1[rr_][cL], C2s = sC2[rr_][cL];        \
            float N0s = sN0[rr_][cL], N1s = sN1[rr_][cL], N2s = sN2[rr_][cL];        \
            float Zs  = sZv[rr_][cL];                                                \
            _Pragma("unroll")                                                        \
            for (int o = 0; o < RPT; ++o) {                                          \
                if (!CHECK || val[o]) {                                              \
                    float dot = fmaf(N0s, cn0p[o].x, fmaf(N1s, cn1p[o].x, N2s * cn2p[o].x)); \
                    float vvs = fmaf(dot, PAf, PBf);                                 \
                    float zds = Zs - czp[o].x;                                       \
                    float cxs = bneg2[o].x + K25NC;                                  \
                    float eas = fmaf(-fabsf(zds), tm5[o], cxs);                      \
                    float e2s = fmaf(dot, vvs, eas);                                 \
                    float ws  = fast_exp2(e2s);                                      \
                    sxl[o] = fmaf(C0s, ws, sxl[o]);                                  \
                    syl[o] = fmaf(C1s, ws, syl[o]);                                  \
                    szl[o] = fmaf(C2s, ws, szl[o]);                                  \
                    swl[o] += ws;                                                    \
                }                                                                    \
            }                                                                        \
        }                                                                            \
    }

    // ---- boundary head: r=0 (o=1 invalid) ----
    #pragma unroll 1
    for (int r = 0; r < RPT - 1; ++r) ROW_BODY(true)
    // ---- steady rows r in [1,10]: both outputs valid, branch-free ----
    #pragma unroll 1
    for (int r = RPT - 1; r <= 2 * RAD; ++r) ROW_BODY(false)
    // ---- boundary tail: r=11 (o=0 invalid) ----
    #pragma unroll 1
    for (int r = 2 * RAD + 1; r < 2 * RAD + RPT; ++r) ROW_BODY(true)

    #undef ROW_BODY

    // ---- epilogue: horizontal-add pairs + leftover, divide, store ----
    const int xo = x0 + tx;
    #pragma unroll
    for (int o = 0; o < RPT; ++o) {
        int y = y0 + ty * RPT + o;
        if (y < HH) {
            float tw = aw2[o].x + aw2[o].y + swl[o];
            float txc = ax2[o].x + ax2[o].y + sxl[o];
            float tyc = ay2[o].x + ay2[o].y + syl[o];
            float tzc = az2[o].x + az2[o].y + szl[o];
            float inv = fast_rcp(tw);
            size_t base = ((size_t)y * WW + xo) * 3;
            out[base + 0] = txc * inv;
            out[base + 1] = tyc * inv;
            out[base + 2] = tzc * inv;
        }
    }
}

extern "C" void kernel_launch(void* const* d_in, const int* in_sizes, int n_in,
                              void* d_out, int out_size, void* d_ws, size_t ws_size,
                              hipStream_t stream) {
    const float* in = (const float*)d_in[0];
    float* out = (float*)d_out;
    dim3 grid((WW + TX - 1) / TX, (HH + TY - 1) / TY);    // 60 x 68
    dim3 block(TX, BDY);                                   // 256 threads = 4 waves
    hipLaunchKernelGGL(denoise_kernel, grid, block, 0, stream, in, out);
}

// Round 17
// 106.102 us; speedup vs baseline: 1.0692x; 1.0692x over previous
//
#include <hip/hip_runtime.h>
#include <math.h>

#define HH 1080
#define WW 1920
#define RAD 5
#define TX 32
#define TY 16            // 16 rows/block; LDS 30720B -> 5 blocks x 4 waves = 20 waves/CU
#define RPT 2
#define BDY 8            // 32x8 = 256 threads = 4 waves (R12 lesson: keep 4-wave blocks)
#define LR (TY + 2*RAD)  // 26
#define LC (TX + 2*RAD)  // 42

__device__ __forceinline__ float fast_rcp(float x) {
#if __has_builtin(__builtin_amdgcn_rcpf)
    return __builtin_amdgcn_rcpf(x);
#else
    return 1.0f / x;
#endif
}
__device__ __forceinline__ float fast_rsq(float x) {
#if __has_builtin(__builtin_amdgcn_rsqf)
    return __builtin_amdgcn_rsqf(x);
#else
    return rsqrtf(x);
#endif
}
__device__ __forceinline__ float fast_exp2(float x) {
#if __has_builtin(__builtin_amdgcn_exp2f)
    return __builtin_amdgcn_exp2f(x);
#else
    return exp2f(x);
#endif
}

// Weight: w = exp(-d2/8) * clip(dot,0,1)^128 * exp(-|tz-z| / max(dz*sqrt(d2), 1e-4))
// One exp2; quadratic ln(1+t) ~= t - t^2/2 for the ^128 term with t = dot-1 folded out:
//   e2 = fma(dot, fma(dot, -C/2, 2C), e2a'),  C = 128*log2e
//   e2a' = fma(-|zd|, tm[d2], cx'[d2]),  cx'[d2] = -d2*log2e/8 - 1.5C
//   tm[d2] = min(rdz*rsqrt(d2), 1e4*log2e),  rdz = min(log2e*rcp(dz), 1e10)
// tm tables RATIO-CHAIN across tap-rows (one step at RPT=2): tm[o=1] at row r equals
// tm[o=0] at row r-1 scaled by rr1 = rdz[1]/rdz[0] (cancels exactly); only tmu0 fresh
// (6 rsq/row). Clamp AFTER chaining. rdz clamp keeps rr1 finite-positive.
// Center tap: rsqrt(0)=inf -> tm=BIG; zd==0 -> fma(-0,BIG,cx)=cx; dot==1 -> w=1. Exact.
// dot=0 (clip / zero-padded halo mask) -> e2 <= -277 -> w=0 == reference t_m mask.
// Validated fusion numerics R2-R14: absmax 3.9e-3 vs threshold 2e-2.
// ===== R17: verified-best revert (R13). Closed branches and their evidence: =====
//   R2  full row-loop unroll -> 256 VGPR spill catastrophe (4.5 GB scratch traffic)
//   R4  LDS table for wave-uniform d2 -> per-body addr math costs more than it saves
//   R9/R10 deep loop-carried chains -> partial scratch demotion (WRITE 24->46MB)
//   R11 launch_bounds wave demand -> forced VGPR=48, 233MB spill
//   R12 5-wave (320-thr) blocks -> co-residency collapse (occ 22%)
//   R14 f32x2 via __builtin_elementwise_* -> scalarizes (no v_pk_*_f32 from hipcc IR)
//   R15/R16 v_pk_* via inline asm -> WRONG RESULTS (absmax 1e5; op_sel semantics trap)
// Floor arithmetic: 121 taps x 2.07M px x ~12 issue-ops / 1024 SIMDs ~ 100 us @2.4GHz;
// measured 106.4 us (busy product ~103 us-equiv, VALUBusy 87%) = within ~6%. VALU-bound.

__global__ __launch_bounds__(TX*BDY, 4)
void denoise_kernel(const float* __restrict__ in, float* __restrict__ out) {
    __shared__ float4 sA[LR][LC];   // c0,c1,c2,n0   17472 B
    __shared__ float2 sN[LR][LC];   // n1,n2          8736 B
    __shared__ float  sZ[LR][LC];   // z              4368 B -> 30576 B -> 5 blocks/CU

    const int tx = threadIdx.x;
    const int ty = threadIdx.y;
    const int tid = ty * TX + tx;
    const int x0 = blockIdx.x * TX;
    const int y0 = blockIdx.y * TY;

    // ---- stage tile + halo, normalizing normals on the fly ----
    #pragma unroll
    for (int i = 0; i < (LR * LC + TX * BDY - 1) / (TX * BDY); ++i) {
        int idx = tid + i * (TX * BDY);
        if (idx < LR * LC) {
            int r = idx / LC, c = idx % LC;
            int gx = x0 + c - RAD;
            int gy = y0 + r - RAD;
            float4 a = make_float4(0.f, 0.f, 0.f, 0.f);
            float4 b = make_float4(0.f, 0.f, 0.f, 0.f);
            if ((unsigned)gx < (unsigned)WW && (unsigned)gy < (unsigned)HH) {
                const float4* p = reinterpret_cast<const float4*>(in + ((size_t)gy * WW + gx) * 8);
                a = p[0];
                b = p[1];
            }
            float nn = a.w * a.w + b.x * b.x + b.y * b.y;
            float s = fast_rsq(fmaxf(nn, 1e-20f));
            sA[r][c] = make_float4(a.x, a.y, a.z, a.w * s);
            sN[r][c] = make_float2(b.x * s, b.y * s);
            sZ[r][c] = b.z;
        }
    }
    __syncthreads();

    // ---- per-thread centers: 2 vertically adjacent outputs ----
    float cn0[RPT], cn1[RPT], cn2[RPT], cz[RPT], rdz[RPT];
    #pragma unroll
    for (int o = 0; o < RPT; ++o) {
        int rr = ty * RPT + RAD + o, cc = tx + RAD;
        float4 A = sA[rr][cc];
        float2 N = sN[rr][cc];
        cn0[o] = A.w; cn1[o] = N.x; cn2[o] = N.y; cz[o] = sZ[rr][cc];
        int gy = y0 + ty * RPT + o;
        float dzv = 1.0f;
        if (gy < HH) dzv = in[(((size_t)gy * WW) + (x0 + tx)) * 8 + 7];  // tail-tile guard
        rdz[o] = fminf(1.4426950408889634f * fast_rcp(dzv), 1e10f);  // log2e folded; finite
    }
    const float rr1 = rdz[1] * fast_rcp(rdz[0]);   // chain ratio, finite positive

    float accx[RPT] = {0.f, 0.f};
    float accy[RPT] = {0.f, 0.f};
    float accz[RPT] = {0.f, 0.f};
    float accw[RPT] = {0.f, 0.f};

    // unclamped tm chain state (zero-init: invalid slots chain to 0, gated by val[])
    float tmu0[RAD + 1] = {}, tmu1[RAD + 1] = {};

    // ROW_BODY(CHECK): one tap-row. Rotate the 1-step tm chain, compute 6 fresh rsq
    // for o=0's new dy, clamp into tmv (value-select, compile-time (o,k)), build cxv,
    // then 11 x RPT unrolled bodies with compile-time k = |dx-RAD|.
    // Steady body: 11 VALU + 1 exp2.
    #define ROW_BODY(CHECK)                                                          \
    {                                                                                \
        _Pragma("unroll")                                                            \
        for (int k = 0; k <= RAD; ++k) tmu1[k] = tmu0[k] * rr1;                      \
        if (!CHECK || r <= 2 * RAD) {   /* fresh dy only while it can become valid */\
            int dy0 = r - RAD;                                                      \
            float dy0sq = (float)(dy0 * dy0);                                       \
            _Pragma("unroll")                                                       \
            for (int k = 0; k <= RAD; ++k)                                          \
                tmu0[k] = rdz[0] * fast_rsq(dy0sq + (float)(k * k));                \
        }                                                                            \
        float tmv[RPT][RAD + 1], cxv[RPT][RAD + 1];                                  \
        bool  val[RPT];                                                              \
        _Pragma("unroll")                                                            \
        for (int o = 0; o < RPT; ++o) {                                              \
            int dy = r - RAD - o;                                                    \
            val[o] = (dy >= -RAD) && (dy <= RAD);                                    \
            if (!CHECK || val[o]) {                                                  \
                float dy2f = (float)(dy * dy);                                       \
                float bneg = fmaf(dy2f, -0.18033688011112042f, -276.997447850681f);  \
                _Pragma("unroll")                                                    \
                for (int k = 0; k <= RAD; ++k) {                                     \
                    float tmuk = (o == 0) ? tmu0[k] : tmu1[k];                       \
                    cxv[o][k] = bneg + (float)(k * k) * -0.18033688011112042f;       \
                    tmv[o][k] = fminf(tmuk, 14426.950408889634f);                    \
                }                                                                    \
            }                                                                        \
        }                                                                            \
        _Pragma("unroll")                                                            \
        for (int dx = 0; dx < 2 * RAD + 1; ++dx) {                                   \
            float4 A  = sA[ty * RPT + r][tx + dx];                                   \
            float2 N  = sN[ty * RPT + r][tx + dx];                                   \
            float  tz = sZ[ty * RPT + r][tx + dx];                                   \
            const int k = (dx < RAD) ? (RAD - dx) : (dx - RAD);                      \
            _Pragma("unroll")                                                        \
            for (int o = 0; o < RPT; ++o) {                                          \
                if (!CHECK || val[o]) {                                              \
                    float dot = fmaf(A.w, cn0[o], fmaf(N.x, cn1[o], N.y * cn2[o]));  \
                    float vv  = fmaf(dot, -92.332482616893665f, 369.32993046757466f); \
                    float zd  = tz - cz[o];                                          \
                    float e2a = fmaf(-fabsf(zd), tmv[o][k], cxv[o][k]);              \
                    float e2  = fmaf(dot, vv, e2a);                                  \
                    float w   = fast_exp2(e2);                                       \
                    accx[o] = fmaf(A.x, w, accx[o]);                                 \
                    accy[o] = fmaf(A.y, w, accy[o]);                                 \
                    accz[o] = fmaf(A.z, w, accz[o]);                                 \
                    accw[o] += w;                                                    \
                }                                                                    \
            }                                                                        \
        }                                                                            \
    }

    // ---- boundary head: r=0 (o=1 invalid) ----
    #pragma unroll 1
    for (int r = 0; r < RPT - 1; ++r) ROW_BODY(true)
    // ---- steady rows r in [1,10]: both outputs valid, branch-free ----
    #pragma unroll 1
    for (int r = RPT - 1; r <= 2 * RAD; ++r) ROW_BODY(false)
    // ---- boundary tail: r=11 (o=0 invalid) ----
    #pragma unroll 1
    for (int r = 2 * RAD + 1; r < 2 * RAD + RPT; ++r) ROW_BODY(true)

    #undef ROW_BODY

    // ---- epilogue (y-guard for the partial 68th row-block) ----
    const int xo = x0 + tx;
    #pragma unroll
    for (int o = 0; o < RPT; ++o) {
        int y = y0 + ty * RPT + o;
        if (y < HH) {
            float inv = fast_rcp(accw[o]);
            size_t base = ((size_t)y * WW + xo) * 3;
            out[base + 0] = accx[o] * inv;
            out[base + 1] = accy[o] * inv;
            out[base + 2] = accz[o] * inv;
        }
    }
}

extern "C" void kernel_launch(void* const* d_in, const int* in_sizes, int n_in,
                              void* d_out, int out_size, void* d_ws, size_t ws_size,
                              hipStream_t stream) {
    const float* in = (const float*)d_in[0];
    float* out = (float*)d_out;
    dim3 grid((WW + TX - 1) / TX, (HH + TY - 1) / TY);    // 60 x 68
    dim3 block(TX, BDY);                                   // 256 threads = 4 waves
    hipLaunchKernelGGL(denoise_kernel, grid, block, 0, stream, in, out);
}